// Round 8
// baseline (68.261 us; speedup 1.0000x reference)
//
#include <hip/hip_runtime.h>
#include <hip/hip_bf16.h>

#define NN 3072
#define RR 8

typedef float f4 __attribute__((ext_vector_type(4)));

// Pass 1: pure fill of the default pattern [1,0,0,0,0,0,0,0] per pair.
// Grid-stride: 2048 blocks x 256 threads x 36 stores = 18,874,368 f4.
// Per-instruction contiguity (lane l -> consecutive 16B), value invariant
// per thread since the stride (524288) is even.
__global__ __launch_bounds__(256) void fill_default(f4* __restrict__ out)
{
    const int tid = blockIdx.x * 256 + threadIdx.x;   // < 524288
    f4 v;
    v.x = (tid & 1) ? 0.0f : 1.0f;
    v.y = 0.0f; v.z = 0.0f; v.w = 0.0f;
#pragma unroll
    for (int k = 0; k < 36; ++k) {
        out[tid + k * 524288] = v;
    }
}

// Pass 2: batch sorted -> same-batch pairs are contiguous diagonal blocks.
// One wave per row: binary-search [lo,hi), then write the ENTIRE block row
// (product where selected, default otherwise) so every 64B line is fully
// covered -> no partial-line RMW against HBM.
__global__ __launch_bounds__(256) void scatter_pairs(
    const float* __restrict__ z,       // [N, R]
    const int*   __restrict__ seg,     // [N, N]
    const int*   __restrict__ cls,     // [N]
    const int*   __restrict__ batch,   // [N]
    float*       __restrict__ out)     // [N, N, R]
{
    const int i    = (blockIdx.x * 256 + threadIdx.x) >> 6;  // one wave per row
    const int lane = threadIdx.x & 63;

    // labels in [0,27): "not in {24,25,26}" <=> (< 24)
    const int ci = cls[i];
    if (ci >= 24) return;                  // whole row stays default
    const int bi = batch[i];

    // [lo,hi) = columns with batch[j] == bi (uniform binary search, L2-hot)
    int l = 0, r = NN;
    while (l < r) { const int m = (l + r) >> 1; if (batch[m] <  bi) l = m + 1; else r = m; }
    const int lo = l;
    r = NN;
    while (l < r) { const int m = (l + r) >> 1; if (batch[m] <= bi) l = m + 1; else r = m; }
    const int hi = l;

    const f4* zip = (const f4*)(z + (long long)i * RR);
    const f4 a0 = zip[0], a1 = zip[1];
    const long long rowbase = (long long)i * NN;

    const f4 d0 = {1.0f, 0.0f, 0.0f, 0.0f};
    const f4 d1 = {0.0f, 0.0f, 0.0f, 0.0f};

    for (int j = lo + lane; j < hi; j += 64) {
        // seg_matrix in {0,1}; +eye -> diagonal never selected: (s==0 && i!=j)
        const int s = seg[rowbase + j];
        const bool pm = (s == 0) & (i != j) & (cls[j] < 24);

        const f4* zjp = (const f4*)(z + (long long)j * RR);
        const f4 b0 = zjp[0], b1 = zjp[1];

        f4* o = (f4*)(out + (rowbase + j) * RR);
        o[0] = pm ? (a0 * b0) : d0;
        o[1] = pm ? (a1 * b1) : d1;
    }
}

extern "C" void kernel_launch(void* const* d_in, const int* in_sizes, int n_in,
                              void* d_out, int out_size, void* d_ws, size_t ws_size,
                              hipStream_t stream) {
    const float* z     = (const float*)d_in[0];
    const int*   seg   = (const int*)d_in[1];
    const int*   cls   = (const int*)d_in[2];
    const int*   batch = (const int*)d_in[3];
    float* out = (float*)d_out;

    // Pass 1: 2048 blocks, grid-stride fill
    fill_default<<<2048, 256, 0, stream>>>((f4*)out);

    // Pass 2: one wave per row -> 3072 waves -> 768 blocks
    scatter_pairs<<<(NN * 64) / 256, 256, 0, stream>>>(z, seg, cls, batch, out);
}

// Round 9
// 67.042 us; speedup vs baseline: 1.0182x; 1.0182x over previous
//
#include <hip/hip_runtime.h>
#include <hip/hip_bf16.h>

#define NN 3072
#define RR 8

typedef float f4 __attribute__((ext_vector_type(4)));

// Single fused pass. blockIdx.y = row i (batch[i], cls[i] wave-uniform ->
// scalar loads). Two lanes per pair: lane owns one float4 (16B) of the 32B
// output -> every wave stores a contiguous 1 KiB block, unconditionally.
// batch is sorted, so batch[i]==batch[j] gates the expensive path: only
// ~6% of waves (diagonal blocks) load seg/cls[j]/z at all.
__global__ __launch_bounds__(256) void frd_fused(
    const float* __restrict__ z,       // [N, R]
    const int*   __restrict__ seg,     // [N, N]
    const int*   __restrict__ cls,     // [N]
    const int*   __restrict__ batch,   // [N]
    float*       __restrict__ out)     // [N, N, R]
{
    const int i = blockIdx.y;                        // wave-uniform
    const int t = blockIdx.x * 256 + threadIdx.x;    // 0 .. 2*NN-1
    const int j = t >> 1;
    const int h = t & 1;

    const int bi = batch[i];                         // scalar load
    const int bj = batch[j];                         // coalesced (2 lanes/word)

    f4 r;
    r.x = h ? 0.0f : 1.0f;
    r.y = 0.0f; r.z = 0.0f; r.w = 0.0f;

    if (bi == bj) {                                  // skipped by 94% of waves
        // seg_matrix in {0,1}; +eye -> diagonal never selected: (s==0 && i!=j)
        const int s = seg[(long long)i * NN + j];
        // labels in [0,27): "not in {24,25,26}" <=> (< 24)
        const bool pm = (s == 0) & (i != j) & (cls[i] < 24) & (cls[j] < 24);
        if (pm) {
            const f4 a = *(const f4*)(z + i * RR + h * 4);
            const f4 b = *(const f4*)(z + j * RR + h * 4);
            r = a * b;
        }
    }

    // dense, contiguous 16B/lane store stream
    *(f4*)(out + (long long)i * (NN * RR) + (long long)t * 4) = r;
}

extern "C" void kernel_launch(void* const* d_in, const int* in_sizes, int n_in,
                              void* d_out, int out_size, void* d_ws, size_t ws_size,
                              hipStream_t stream) {
    const float* z     = (const float*)d_in[0];
    const int*   seg   = (const int*)d_in[1];
    const int*   cls   = (const int*)d_in[2];
    const int*   batch = (const int*)d_in[3];
    float* out = (float*)d_out;

    dim3 grid((NN * 2) / 256, NN);   // (24, 3072)
    frd_fused<<<grid, dim3(256), 0, stream>>>(z, seg, cls, batch, out);
}

// Round 10
// 62.960 us; speedup vs baseline: 1.0842x; 1.0648x over previous
//
#include <hip/hip_runtime.h>
#include <hip/hip_bf16.h>

#define NN 3072
#define RR 8

typedef float f4 __attribute__((ext_vector_type(4)));

#define FILL_BLOCKS 2304     // 9 per CU
#define F4_PER_BLOCK 8192    // 128 KiB contiguous per block; 2304*8192 = NN*NN*2

// Pass 1: persistent fill. Each block owns a contiguous 128 KiB chunk;
// each iteration the block stores a contiguous 4 KiB (lane l -> 16B).
// f4-index parity == threadIdx parity (stride 256 is even), so the
// [1,0,0,0] / [0,0,0,0] alternation is thread-invariant.
__global__ __launch_bounds__(256) void fill_default(f4* __restrict__ out)
{
    const long long base = (long long)blockIdx.x * F4_PER_BLOCK + threadIdx.x;
    f4 v;
    v.x = (threadIdx.x & 1) ? 0.0f : 1.0f;
    v.y = 0.0f; v.z = 0.0f; v.w = 0.0f;
#pragma unroll
    for (int k = 0; k < F4_PER_BLOCK / 256; ++k) {
        out[base + k * 256] = v;
    }
}

// Pass 2 (verbatim from round 6, the 60.7 µs best): batch sorted -> same-
// batch pairs are contiguous diagonal blocks (~6%). One wave per row:
// binary-search [lo,hi), scan those columns, scatter z[i]*z[j] if selected.
__global__ __launch_bounds__(256) void scatter_pairs(
    const float* __restrict__ z,       // [N, R]
    const int*   __restrict__ seg,     // [N, N]
    const int*   __restrict__ cls,     // [N]
    const int*   __restrict__ batch,   // [N]
    float*       __restrict__ out)     // [N, N, R]
{
    const int i    = (blockIdx.x * 256 + threadIdx.x) >> 6;  // one wave per row
    const int lane = threadIdx.x & 63;

    // labels in [0,27): "not in {24,25,26}" <=> (< 24)
    const int ci = cls[i];
    if (ci >= 24) return;                  // whole row stays default
    const int bi = batch[i];

    // [lo,hi) = columns with batch[j] == bi (uniform binary search, L2-hot)
    int l = 0, r = NN;
    while (l < r) { const int m = (l + r) >> 1; if (batch[m] <  bi) l = m + 1; else r = m; }
    const int lo = l;
    r = NN;
    while (l < r) { const int m = (l + r) >> 1; if (batch[m] <= bi) l = m + 1; else r = m; }
    const int hi = l;

    const f4* zip = (const f4*)(z + (long long)i * RR);
    const f4 a0 = zip[0], a1 = zip[1];
    const long long rowbase = (long long)i * NN;

    for (int j = lo + lane; j < hi; j += 64) {
        // seg_matrix in {0,1}; +eye -> diagonal never selected: (s==0 && i!=j)
        const int s = seg[rowbase + j];
        const bool pm = (s == 0) & (i != j) & (cls[j] < 24);
        if (pm) {
            const f4* zjp = (const f4*)(z + (long long)j * RR);
            f4* o = (f4*)(out + (rowbase + j) * RR);
            o[0] = a0 * zjp[0];
            o[1] = a1 * zjp[1];
        }
    }
}

extern "C" void kernel_launch(void* const* d_in, const int* in_sizes, int n_in,
                              void* d_out, int out_size, void* d_ws, size_t ws_size,
                              hipStream_t stream) {
    const float* z     = (const float*)d_in[0];
    const int*   seg   = (const int*)d_in[1];
    const int*   cls   = (const int*)d_in[2];
    const int*   batch = (const int*)d_in[3];
    float* out = (float*)d_out;

    fill_default<<<FILL_BLOCKS, 256, 0, stream>>>((f4*)out);

    // one wave per row -> 3072 waves -> 768 blocks
    scatter_pairs<<<(NN * 64) / 256, 256, 0, stream>>>(z, seg, cls, batch, out);
}